// Round 13
// baseline (323.029 us; speedup 1.0000x reference)
//
#include <hip/hip_runtime.h>
#include <stdint.h>

typedef unsigned short ub16;
typedef __attribute__((ext_vector_type(8))) short short8;
typedef __attribute__((ext_vector_type(4))) float f32x4;
typedef __attribute__((ext_vector_type(4))) unsigned short us4v;

__device__ __forceinline__ float bf2f(ub16 u) {
  union { unsigned int i; float f; } v; v.i = ((unsigned int)u) << 16; return v.f;
}
__device__ __forceinline__ ub16 f2bf(float f) {
  union { float f; unsigned int i; } v; v.f = f;
  return (ub16)((v.i + 0x7FFFu + ((v.i >> 16) & 1u)) >> 16);
}
__device__ __forceinline__ f32x4 zero4() { f32x4 v = {0.f, 0.f, 0.f, 0.f}; return v; }
__device__ __forceinline__ f32x4 mfma16(short8 a, short8 b, f32x4 c) {
  return __builtin_amdgcn_mfma_f32_16x16x32_bf16(a, b, c, 0, 0, 0);
}
__device__ __forceinline__ float rmax16(float x) {
  x = fmaxf(x, __shfl_xor(x, 1)); x = fmaxf(x, __shfl_xor(x, 2));
  x = fmaxf(x, __shfl_xor(x, 4)); x = fmaxf(x, __shfl_xor(x, 8)); return x;
}
__device__ __forceinline__ float rsum16(float x) {
  x += __shfl_xor(x, 1); x += __shfl_xor(x, 2);
  x += __shfl_xor(x, 4); x += __shfl_xor(x, 8); return x;
}

// async global->LDS 16B (wave-uniform LDS base + lane*16 implicit)
__device__ __forceinline__ void gload16(const ub16* g, ub16* l) {
  __builtin_amdgcn_global_load_lds(
      (const __attribute__((address_space(1))) void*)g,
      (__attribute__((address_space(3))) void*)l, 16, 0, 0);
}

// ---- BK=32 staging: 128 rows x 32 cols (8KB). LDS dest linear; global source
// slot pre-swizzled with slot ^= (row>>1)&3 so the swizzled reads (2-way bank,
// free per m136) see the right data. Both-sides-same-involution (rule #21).
__device__ __forceinline__ void stage_tile32(const ub16* __restrict__ src, ub16* ldsbase,
                                             int wid, int lane) {
  const int rr = lane >> 2;                    // row within 16-row chunk
  const int sslot = (lane & 3) ^ ((rr >> 1) & 3);
#pragma unroll
  for (int c = 0; c < 2; ++c) {
    int chunk = wid * 2 + c;                   // 8 chunks of 16 rows (1KB each)
    int row = chunk * 16 + rr;
    gload16(src + (size_t)row * 512 + sslot * 8,
            (ub16*)((char*)ldsbase + chunk * 1024));
  }
}

// BK=32 compute: 16 MFMAs per wave. SWAP=true: acc = mfma(B,A).
template<bool SWAP>
__device__ __forceinline__ void gemm_compute32(const ub16* Ab, const ub16* Bb, int wm, int wn,
                                               int l15, int lg, f32x4 acc[4][4]) {
  short8 af[4], bfr[4];
#pragma unroll
  for (int mf = 0; mf < 4; ++mf) {
    int row = wm * 64 + mf * 16 + l15;
    af[mf] = *(const short8*)((const char*)Ab + row * 64 +
                              ((lg ^ ((row >> 1) & 3)) * 16));
  }
#pragma unroll
  for (int nf = 0; nf < 4; ++nf) {
    int row = wn * 64 + nf * 16 + l15;
    bfr[nf] = *(const short8*)((const char*)Bb + row * 64 +
                               ((lg ^ ((row >> 1) & 3)) * 16));
  }
#pragma unroll
  for (int mf = 0; mf < 4; ++mf)
#pragma unroll
    for (int nf = 0; nf < 4; ++nf)
      acc[mf][nf] = SWAP ? mfma16(bfr[nf], af[mf], acc[mf][nf])
                         : mfma16(af[mf], bfr[nf], acc[mf][nf]);
}

// Pipelined K=512 loop (16 steps of BK=32), quad-buffer 32KB total.
// Per step: issue STAGE(next) -> compute(cur) -> vmcnt(0)+barrier.
// Stage latency hides under compute; one barrier per step; 5 blocks/CU kept.
template<bool SWAP>
__device__ __forceinline__ void gemm_k512(const ub16* Ap, const ub16* Bp, ub16* lds,
                                          int wid, int lane, int wm, int wn, int l15, int lg,
                                          f32x4 acc[4][4]) {
  // buffers (ub16 units): A0@0, B0@4096, A1@8192, B1@12288  (8KB each)
  stage_tile32(Ap, lds, wid, lane);
  stage_tile32(Bp, lds + 4096, wid, lane);
  asm volatile("s_waitcnt vmcnt(0)" ::: "memory");
  __syncthreads();
#pragma unroll
  for (int kb = 0; kb < 16; ++kb) {
    ub16* Acur = lds + (kb & 1) * 8192;
    ub16* Bcur = Acur + 4096;
    if (kb + 1 < 16) {
      ub16* Anxt = lds + ((kb + 1) & 1) * 8192;
      stage_tile32(Ap + (kb + 1) * 32, Anxt, wid, lane);
      stage_tile32(Bp + (kb + 1) * 32, Anxt + 4096, wid, lane);
    }
    gemm_compute32<SWAP>(Acur, Bcur, wm, wn, l15, lg, acc);
    asm volatile("s_waitcnt vmcnt(0)" ::: "memory");
    __syncthreads();
  }
}

// XCD-bijective remap (nwg%8==0), n-tile fastest within an XCD.
__device__ __forceinline__ void xcd_remap(int nx, int& m0, int& n0) {
  int bid = blockIdx.x, nwg = gridDim.x;
  int cpx = nwg >> 3;
  int wgid = (bid & 7) * cpx + (bid >> 3);
  n0 = (wgid % nx) * 128;
  m0 = (wgid / nx) * 128;
}

// ---------------- P0: x (fp32) -> xb (bf16) ----------------
__global__ void k_cvt(const float* __restrict__ x, ub16* __restrict__ xb) {
  int i = blockIdx.x * 256 + threadIdx.x;
  f32x4 v = *(const f32x4*)&x[(size_t)i * 4];
  us4v o;
#pragma unroll
  for (int e = 0; e < 4; ++e) o[e] = f2bf(v[e]);
  *(us4v*)&xb[(size_t)i * 4] = o;
}

// ---------------- P1: weight transpose + bf16  WT[n][k] = w[k][n] ----------------
__global__ void k_prep_wt(const float* s0, const float* s1, const float* s2,
                          const float* s3, const float* s4,
                          ub16* d0, ub16* d1, ub16* d2, ub16* d3, ub16* d4) {
  const float* src; ub16* dst; int N;
  switch (blockIdx.z) {
    case 0: src = s0; dst = d0; N = 512; break;
    case 1: src = s1; dst = d1; N = 512; break;
    case 2: src = s2; dst = d2; N = 512; break;
    case 3: src = s3; dst = d3; N = 512; break;
    default: src = s4; dst = d4; N = 1024; break;
  }
  int n0 = blockIdx.x * 64, k0 = blockIdx.y * 64;
  if (n0 >= N) return;
  __shared__ float tile[64][65];
#pragma unroll
  for (int i = 0; i < 16; ++i) {
    int idx = i * 256 + threadIdx.x, r = idx >> 6, c = idx & 63;
    tile[r][c] = src[(size_t)(k0 + r) * N + n0 + c];
  }
  __syncthreads();
#pragma unroll
  for (int i = 0; i < 16; ++i) {
    int idx = i * 256 + threadIdx.x, r = idx >> 6, c = idx & 63;
    dst[(size_t)(n0 + r) * 512 + k0 + c] = f2bf(tile[c][r]);
  }
}

// ---------------- P2: kv1 = lkv@w_kvy+b ; q2p = lq@w_q+b ; k1 (scaled), v1T, bias1 ----------------
__global__ void k_prep_small(const float* __restrict__ lkv, const float* __restrict__ w_kvy,
                             const float* __restrict__ b_kvy, const float* __restrict__ lq,
                             const float* __restrict__ w_q, const float* __restrict__ b_q,
                             const float* __restrict__ pe1,
                             ub16* __restrict__ k1, ub16* __restrict__ v1T,
                             float* __restrict__ bias1, ub16* __restrict__ q2p) {
  int j = blockIdx.x, t = threadIdx.x;  // 64 threads
  __shared__ float wcol[512];
  __shared__ float red[64];
  const float* W; const float* src; float bias; int NC, jj;
  if (j < 1024) { W = w_kvy; NC = 1024; src = lkv; jj = j;        bias = b_kvy[j]; }
  else          { W = w_q;   NC = 512;  src = lq;  jj = j - 1024; bias = b_q[jj]; }
#pragma unroll
  for (int e = 0; e < 8; ++e) wcol[t * 8 + e] = W[(size_t)(t * 8 + e) * NC + jj];
  __syncthreads();
  float acc = bias;
  for (int k = 0; k < 512; ++k) acc += src[(size_t)t * 512 + k] * wcol[k];
  if (j < 512) {
    int h = j >> 6, d = j & 63;
    k1[(size_t)(h * 64 + t) * 64 + d] = f2bf(acc * 0.125f);
  } else if (j < 1024) {
    int h = (j - 512) >> 6, d = (j - 512) & 63;
    v1T[(size_t)(h * 64 + d) * 64 + t] = f2bf(acc);
    red[t] = pe1[h * 64 + t] * acc;
    __syncthreads();
    for (int s = 32; s > 0; s >>= 1) { if (t < s) red[t] += red[t + s]; __syncthreads(); }
    if (t == 0) bias1[h * 64 + d] = red[0];
  } else {
    int h = jj >> 6, d = jj & 63;
    q2p[(size_t)(h * 64 + t) * 64 + d] = f2bf(acc * 0.125f);
  }
}

// ---------------- P3: WqkT + bias_s ----------------
__global__ __launch_bounds__(256) void k_prep_wqk(
    const float* __restrict__ w_q2, const float* __restrict__ b_q2,
    const ub16* __restrict__ k1, ub16* __restrict__ WqkT,
    float* __restrict__ biass) {
  int ha = blockIdx.x, h = ha >> 6, t = threadIdx.x;
  __shared__ float kr[64];
  if (t < 64) kr[t] = bf2f(k1[(size_t)ha * 64 + t]);
  __syncthreads();
#pragma unroll
  for (int i = 0; i < 2; ++i) {
    int kin = t + i * 256;
    const float* wrow = &w_q2[(size_t)kin * 512 + h * 64];
    float acc = 0.f;
#pragma unroll
    for (int d4 = 0; d4 < 16; ++d4) {
      f32x4 wv = *(const f32x4*)&wrow[d4 * 4];
      acc += wv[0] * kr[d4 * 4] + wv[1] * kr[d4 * 4 + 1] +
             wv[2] * kr[d4 * 4 + 2] + wv[3] * kr[d4 * 4 + 3];
    }
    WqkT[(size_t)ha * 512 + kin] = f2bf(acc);
  }
  if (t == 0) {
    float acc = 0.f;
    for (int d = 0; d < 64; ++d) acc += b_q2[h * 64 + d] * kr[d];
    biass[ha] = acc;
  }
}

// ---------------- S1a: scores GEMM (xb@Wqk+bias_s) + per-wave softmax + PV + bias1 -> o1 ----------------
__global__ __launch_bounds__(256) void k_s1a(
    const ub16* __restrict__ xb, const ub16* __restrict__ WqkT,
    const float* __restrict__ biass, const ub16* __restrict__ v1T,
    const float* __restrict__ bias1, ub16* __restrict__ o1) {
  __shared__ ub16 lds[16384];  // 32KB staging; reused as 4x8KB P buffers
  const int tid = threadIdx.x, lane = tid & 63, wid = tid >> 6;
  const int wm = wid >> 1, wn = wid & 1;
  const int l15 = lane & 15, lg = lane >> 4;
  int m0, n0;
  xcd_remap(4, m0, n0);

  f32x4 acc[4][4];
#pragma unroll
  for (int a = 0; a < 4; ++a)
#pragma unroll
    for (int b = 0; b < 4; ++b) acc[a][b] = zero4();

  gemm_k512<false>(xb + (size_t)m0 * 512, WqkT + (size_t)n0 * 512, lds,
                   wid, lane, wm, wn, l15, lg, acc);

  __syncthreads();
  const int h = (n0 >> 6) + wn;
  char* Pl = (char*)lds + wid * 8192;
  float bsv[4];
#pragma unroll
  for (int nf = 0; nf < 4; ++nf) bsv[nf] = biass[h * 64 + nf * 16 + l15];
  float dinv[4][4];
#pragma unroll
  for (int mf = 0; mf < 4; ++mf) {
#pragma unroll
    for (int r = 0; r < 4; ++r) {
      float s0 = acc[mf][0][r] + bsv[0], s1 = acc[mf][1][r] + bsv[1];
      float s2 = acc[mf][2][r] + bsv[2], s3 = acc[mf][3][r] + bsv[3];
      float mx = rmax16(fmaxf(fmaxf(s0, s1), fmaxf(s2, s3)));
      float p0 = __expf(s0 - mx), p1 = __expf(s1 - mx);
      float p2 = __expf(s2 - mx), p3 = __expf(s3 - mx);
      float sm = rsum16(p0 + p1 + p2 + p3);
      dinv[mf][r] = 1.0f / sm;
      int tr = mf * 16 + lg * 4 + r;
      char* rb = Pl + tr * 128;
      int sw = (tr & 7) << 4;
      *(ub16*)(rb + (((0 * 16 + l15) * 2) ^ sw)) = f2bf(p0);
      *(ub16*)(rb + (((1 * 16 + l15) * 2) ^ sw)) = f2bf(p1);
      *(ub16*)(rb + (((2 * 16 + l15) * 2) ^ sw)) = f2bf(p2);
      *(ub16*)(rb + (((3 * 16 + l15) * 2) ^ sw)) = f2bf(p3);
    }
  }
  short8 pa[4][2], vb[4][2];
#pragma unroll
  for (int mf = 0; mf < 4; ++mf) {
    int row = mf * 16 + l15;
#pragma unroll
    for (int kf = 0; kf < 2; ++kf)
      pa[mf][kf] = *(const short8*)(Pl + row * 128 + ((kf * 64 + lg * 16) ^ ((row & 7) << 4)));
  }
#pragma unroll
  for (int nf = 0; nf < 4; ++nf)
#pragma unroll
    for (int kf = 0; kf < 2; ++kf)
      vb[nf][kf] = *(const short8*)&v1T[(size_t)(h * 64 + nf * 16 + l15) * 64 + kf * 32 + lg * 8];
  f32x4 oacc[4][4];
#pragma unroll
  for (int a = 0; a < 4; ++a)
#pragma unroll
    for (int b = 0; b < 4; ++b) oacc[a][b] = zero4();
#pragma unroll
  for (int kf = 0; kf < 2; ++kf)
#pragma unroll
    for (int mf = 0; mf < 4; ++mf)
#pragma unroll
      for (int nf = 0; nf < 4; ++nf)
        oacc[mf][nf] = mfma16(pa[mf][kf], vb[nf][kf], oacc[mf][nf]);
  float b1v[4];
#pragma unroll
  for (int nf = 0; nf < 4; ++nf) b1v[nf] = bias1[h * 64 + nf * 16 + l15];
#pragma unroll
  for (int mf = 0; mf < 4; ++mf)
#pragma unroll
    for (int nf = 0; nf < 4; ++nf)
#pragma unroll
      for (int r = 0; r < 4; ++r) {
        float val = oacc[mf][nf][r] * dinv[mf][r] + b1v[nf];
        o1[(size_t)(m0 + wm * 64 + mf * 16 + lg * 4 + r) * 512 + h * 64 + nf * 16 + l15] = f2bf(val);
      }
}

// ---------------- MLP1a (also MLP2 layer 1): swap epilogue, out = silu(in@W1+b1) ----------------
__global__ __launch_bounds__(256) void k_mlp1a(
    const ub16* __restrict__ in, const ub16* __restrict__ W1T,
    const float* __restrict__ b1, ub16* __restrict__ h1) {
  __shared__ ub16 lds[16384];
  const int tid = threadIdx.x, lane = tid & 63, wid = tid >> 6;
  const int wm = wid >> 1, wn = wid & 1;
  const int l15 = lane & 15, lg = lane >> 4;
  int m0, n0;
  xcd_remap(4, m0, n0);
  f32x4 acc[4][4];
#pragma unroll
  for (int a = 0; a < 4; ++a)
#pragma unroll
    for (int b = 0; b < 4; ++b) acc[a][b] = zero4();
  gemm_k512<true>(in + (size_t)m0 * 512, W1T + (size_t)n0 * 512, lds,
                  wid, lane, wm, wn, l15, lg, acc);
#pragma unroll
  for (int mf = 0; mf < 4; ++mf) {
    int m = m0 + wm * 64 + mf * 16 + l15;
#pragma unroll
    for (int nf = 0; nf < 4; ++nf) {
      int nb = n0 + wn * 64 + nf * 16 + lg * 4;
      f32x4 bb = *(const f32x4*)&b1[nb];
      us4v pk;
#pragma unroll
      for (int r = 0; r < 4; ++r) {
        float v = acc[mf][nf][r] + bb[r];
        v = v / (1.0f + __expf(-v));  // silu
        pk[r] = f2bf(v);
      }
      *(us4v*)&h1[(size_t)m * 512 + nb] = pk;
    }
  }
}

// ---------------- MLP1b: mskip = h1@W2 + b2 + xb(bf16) -> separate bf16 mskip ----------------
__global__ __launch_bounds__(256) void k_mlp1b(
    const ub16* __restrict__ h1, const ub16* __restrict__ W2T,
    const float* __restrict__ b2, const ub16* __restrict__ xb,
    ub16* __restrict__ mskip) {
  __shared__ ub16 lds[16384];
  const int tid = threadIdx.x, lane = tid & 63, wid = tid >> 6;
  const int wm = wid >> 1, wn = wid & 1;
  const int l15 = lane & 15, lg = lane >> 4;
  int m0, n0;
  xcd_remap(4, m0, n0);
  f32x4 acc[4][4];
#pragma unroll
  for (int a = 0; a < 4; ++a)
#pragma unroll
    for (int b = 0; b < 4; ++b) acc[a][b] = zero4();
  gemm_k512<true>(h1 + (size_t)m0 * 512, W2T + (size_t)n0 * 512, lds,
                  wid, lane, wm, wn, l15, lg, acc);
#pragma unroll
  for (int mf = 0; mf < 4; ++mf) {
    int m = m0 + wm * 64 + mf * 16 + l15;
#pragma unroll
    for (int nf = 0; nf < 4; ++nf) {
      int nb = n0 + wn * 64 + nf * 16 + lg * 4;
      f32x4 bb = *(const f32x4*)&b2[nb];
      size_t idx = (size_t)m * 512 + nb;
      us4v xv = *(const us4v*)&xb[idx];
      us4v pk;
#pragma unroll
      for (int r = 0; r < 4; ++r)
        pk[r] = f2bf(acc[mf][nf][r] + bb[r] + bf2f(xv[r]));
      *(us4v*)&mskip[idx] = pk;
    }
  }
}

// ---------------- MLP2b: fin = h2@W2 + b2 (fp32) ----------------
__global__ __launch_bounds__(256) void k_mlp2b(
    const ub16* __restrict__ h2, const ub16* __restrict__ W2T,
    const float* __restrict__ b2, float* __restrict__ fin) {
  __shared__ ub16 lds[16384];
  const int tid = threadIdx.x, lane = tid & 63, wid = tid >> 6;
  const int wm = wid >> 1, wn = wid & 1;
  const int l15 = lane & 15, lg = lane >> 4;
  int m0, n0;
  xcd_remap(4, m0, n0);
  f32x4 acc[4][4];
#pragma unroll
  for (int a = 0; a < 4; ++a)
#pragma unroll
    for (int b = 0; b < 4; ++b) acc[a][b] = zero4();
  gemm_k512<true>(h2 + (size_t)m0 * 512, W2T + (size_t)n0 * 512, lds,
                  wid, lane, wm, wn, l15, lg, acc);
#pragma unroll
  for (int mf = 0; mf < 4; ++mf) {
    int m = m0 + wm * 64 + mf * 16 + l15;
#pragma unroll
    for (int nf = 0; nf < 4; ++nf) {
      int nb = n0 + wn * 64 + nf * 16 + lg * 4;
      f32x4 bb = *(const f32x4*)&b2[nb];
      f32x4 ov;
#pragma unroll
      for (int r = 0; r < 4; ++r) ov[r] = acc[mf][nf][r] + bb[r];
      *(f32x4*)&fin[(size_t)m * 512 + nb] = ov;
    }
  }
}

// ---------------- G4: kv = mskip@w_kvx + b -> Kb (swap, packed d) and VTb (normal, packed t) ----------------
__global__ __launch_bounds__(256) void k_g4(
    const ub16* __restrict__ mskip_bf, const ub16* __restrict__ WT,
    const float* __restrict__ bias, ub16* __restrict__ Kb, ub16* __restrict__ VTb) {
  __shared__ ub16 lds[16384];
  const int tid = threadIdx.x, lane = tid & 63, wid = tid >> 6;
  const int wm = wid >> 1, wn = wid & 1;
  const int l15 = lane & 15, lg = lane >> 4;
  int m0, n0;
  xcd_remap(8, m0, n0);
  f32x4 acc[4][4];
#pragma unroll
  for (int a = 0; a < 4; ++a)
#pragma unroll
    for (int b = 0; b < 4; ++b) acc[a][b] = zero4();
  const int ncb = n0 + wn * 64;
  if (n0 < 512) {  // K half: swapped -> 4 consecutive d per 8B store
    gemm_k512<true>(mskip_bf + (size_t)m0 * 512, WT + (size_t)n0 * 512, lds,
                    wid, lane, wm, wn, l15, lg, acc);
    const int hh = ncb >> 6;
#pragma unroll
    for (int mf = 0; mf < 4; ++mf) {
      int m = m0 + wm * 64 + mf * 16 + l15;
      int b = m >> 12, t = m & 4095;
#pragma unroll
      for (int nf = 0; nf < 4; ++nf) {
        int d0 = nf * 16 + lg * 4;
        f32x4 bb = *(const f32x4*)&bias[ncb + d0];
        us4v pk;
#pragma unroll
        for (int r = 0; r < 4; ++r) pk[r] = f2bf(acc[mf][nf][r] + bb[r]);
        *(us4v*)&Kb[((size_t)(b * 8 + hh) * 4096 + t) * 64 + d0] = pk;
      }
    }
  } else {  // V half: normal -> 4 consecutive t per 8B store
    gemm_k512<false>(mskip_bf + (size_t)m0 * 512, WT + (size_t)n0 * 512, lds,
                     wid, lane, wm, wn, l15, lg, acc);
    const int hv = (ncb >> 6) - 8;
#pragma unroll
    for (int mf = 0; mf < 4; ++mf) {
      int m4 = m0 + wm * 64 + mf * 16 + lg * 4;
      int b = m4 >> 12, t = m4 & 4095;
#pragma unroll
      for (int nf = 0; nf < 4; ++nf) {
        int d = nf * 16 + l15;
        float bb = bias[ncb + d];
        us4v pk;
#pragma unroll
        for (int r = 0; r < 4; ++r) pk[r] = f2bf(acc[mf][nf][r] + bb);
        *(us4v*)&VTb[((size_t)(b * 8 + hv) * 64 + d) * 4096 + t] = pk;
      }
    }
  }
}

// ---------------- A2: flash split attention (16 splits x 256 tokens per (b,h)) ----------------
__global__ __launch_bounds__(256) void k_attn2(
    const ub16* __restrict__ q2p, const ub16* __restrict__ Kb, const ub16* __restrict__ VTb,
    float* __restrict__ m_part, float* __restrict__ l_part,
    float* __restrict__ cs_part, float* __restrict__ o_part) {
  const int tid = threadIdx.x, lane = tid & 63, wid = tid >> 6;
  const int l15 = lane & 15, lg = lane >> 4;
  const int b = blockIdx.z, h = blockIdx.y;
  const int split = blockIdx.x * 4 + wid;  // 0..15
  __shared__ ub16 plds[4 * 64 * 40];
  ub16* pl = plds + wid * 64 * 40;
  short8 qa[4][2];
#pragma unroll
  for (int mf = 0; mf < 4; ++mf)
#pragma unroll
    for (int kf = 0; kf < 2; ++kf)
      qa[mf][kf] = *(const short8*)&q2p[(size_t)(h * 64 + mf * 16 + l15) * 64 + kf * 32 + lg * 8];
  float mr[4][4], lr[4][4], cs[4] = {0.f, 0.f, 0.f, 0.f};
  f32x4 oa[4][4];
#pragma unroll
  for (int a = 0; a < 4; ++a)
#pragma unroll
    for (int r = 0; r < 4; ++r) { mr[a][r] = -1e30f; lr[a][r] = 0.f; }
#pragma unroll
  for (int a = 0; a < 4; ++a)
#pragma unroll
    for (int n = 0; n < 4; ++n) oa[a][n] = zero4();
  const size_t kbase = (size_t)(b * 8 + h) * 4096 * 64;
  const size_t vbase = (size_t)(b * 8 + h) * 64 * 4096;
  for (int c = 0; c < 8; ++c) {
    int tb = split * 256 + c * 32;
    short8 kbf[2][2];
#pragma unroll
    for (int nf = 0; nf < 2; ++nf)
#pragma unroll
      for (int kf = 0; kf < 2; ++kf)
        kbf[nf][kf] = *(const short8*)&Kb[kbase + (size_t)(tb + nf * 16 + l15) * 64 + kf * 32 + lg * 8];
    f32x4 sc[4][2];
#pragma unroll
    for (int a = 0; a < 4; ++a)
#pragma unroll
      for (int n = 0; n < 2; ++n) sc[a][n] = zero4();
#pragma unroll
    for (int kf = 0; kf < 2; ++kf)
#pragma unroll
      for (int mf = 0; mf < 4; ++mf)
#pragma unroll
        for (int nf = 0; nf < 2; ++nf)
          sc[mf][nf] = mfma16(qa[mf][kf], kbf[nf][kf], sc[mf][nf]);
    float al[4][4];
#pragma unroll
    for (int mf = 0; mf < 4; ++mf)
#pragma unroll
      for (int r = 0; r < 4; ++r) {
        float cm = rmax16(fmaxf(sc[mf][0][r], sc[mf][1][r]));
        float nm = fmaxf(mr[mf][r], cm);
        float a_ = __expf(mr[mf][r] - nm);
        float p0 = __expf(sc[mf][0][r] - nm), p1 = __expf(sc[mf][1][r] - nm);
        float rs = rsum16(p0 + p1);
        lr[mf][r] = lr[mf][r] * a_ + rs;
        mr[mf][r] = nm;
        al[mf][r] = a_;
        int ar = mf * 16 + lg * 4 + r;
        char* rb = (char*)pl + ar * 80;
        *(ub16*)(rb + (0 * 16 + l15) * 2) = f2bf(p0);
        *(ub16*)(rb + (1 * 16 + l15) * 2) = f2bf(p1);
      }
#pragma unroll
    for (int mf = 0; mf < 4; ++mf)
#pragma unroll
      for (int nf = 0; nf < 4; ++nf)
#pragma unroll
        for (int r = 0; r < 4; ++r) oa[mf][nf][r] *= al[mf][r];
    short8 pa[4], vb[4];
#pragma unroll
    for (int mf = 0; mf < 4; ++mf)
      pa[mf] = *(const short8*)((char*)pl + (mf * 16 + l15) * 80 + lg * 16);
#pragma unroll
    for (int nf = 0; nf < 4; ++nf) {
      vb[nf] = *(const short8*)&VTb[vbase + (size_t)(nf * 16 + l15) * 4096 + tb + lg * 8];
#pragma unroll
      for (int e = 0; e < 8; ++e) cs[nf] += bf2f((ub16)vb[nf][e]);
    }
#pragma unroll
    for (int mf = 0; mf < 4; ++mf)
#pragma unroll
      for (int nf = 0; nf < 4; ++nf)
        oa[mf][nf] = mfma16(pa[mf], vb[nf], oa[mf][nf]);
  }
#pragma unroll
  for (int nf = 0; nf < 4; ++nf) {
    cs[nf] += __shfl_xor(cs[nf], 16);
    cs[nf] += __shfl_xor(cs[nf], 32);
  }
  const int pidx = (b * 8 + h) * 16 + split;
  if (lg == 0) {
#pragma unroll
    for (int nf = 0; nf < 4; ++nf) cs_part[(size_t)pidx * 64 + nf * 16 + l15] = cs[nf];
  }
  if (l15 == 0) {
#pragma unroll
    for (int mf = 0; mf < 4; ++mf)
#pragma unroll
      for (int r = 0; r < 4; ++r) {
        int a = mf * 16 + lg * 4 + r;
        m_part[(size_t)pidx * 64 + a] = mr[mf][r];
        l_part[(size_t)pidx * 64 + a] = lr[mf][r];
      }
  }
#pragma unroll
  for (int mf = 0; mf < 4; ++mf)
#pragma unroll
    for (int nf = 0; nf < 4; ++nf)
#pragma unroll
      for (int r = 0; r < 4; ++r) {
        int a = mf * 16 + lg * 4 + r, d = nf * 16 + l15;
        o_part[(size_t)pidx * 4096 + a * 64 + d] = oa[mf][nf][r];
      }
}

// ---------------- C2: combine 16 splits + pe2*colsumV -> fin0 (bf16); 4 blocks per (b,h) ----------------
__global__ __launch_bounds__(256) void k_combine(
    const float* __restrict__ m_part, const float* __restrict__ l_part,
    const float* __restrict__ cs_part, const float* __restrict__ o_part,
    const float* __restrict__ pe2, ub16* __restrict__ fin0) {
  int bh = blockIdx.x >> 2, q = blockIdx.x & 3;
  int b = bh >> 3, h = bh & 7;
  int t = threadIdx.x;
  __shared__ float wsp[16][64];
  __shared__ float linv[64];
  __shared__ float cst[64];
  int base = bh * 16;
  if (t < 64) {
    int a = t;
    float M = -1e30f;
    for (int s = 0; s < 16; ++s) M = fmaxf(M, m_part[(size_t)(base + s) * 64 + a]);
    float L = 0.f;
    for (int s = 0; s < 16; ++s) {
      float w = __expf(m_part[(size_t)(base + s) * 64 + a] - M);
      wsp[s][a] = w;
      L += l_part[(size_t)(base + s) * 64 + a] * w;
    }
    linv[a] = 1.0f / L;
  } else if (t < 128) {
    int d = t - 64;
    float c = 0.f;
    for (int s = 0; s < 16; ++s) c += cs_part[(size_t)(base + s) * 64 + d];
    cst[d] = c;
  }
  __syncthreads();
#pragma unroll
  for (int i = 0; i < 4; ++i) {
    int e = q * 1024 + i * 256 + t, a = e >> 6, d = e & 63;
    float acc = 0.f;
#pragma unroll
    for (int s = 0; s < 16; ++s) acc += o_part[(size_t)(base + s) * 4096 + e] * wsp[s][a];
    float val = acc * linv[a] + pe2[h * 64 + a] * cst[d];
    fin0[(size_t)(b * 64 + a) * 512 + h * 64 + d] = f2bf(val);
  }
}

// ---------------- F: out = xb(bf16) + fin_upsampled + mskip(bf16) ----------------
__global__ void k_final(const ub16* __restrict__ xb, const float* __restrict__ fin,
                        const ub16* __restrict__ mskip_bf, float* __restrict__ out) {
  int i = blockIdx.x * 256 + threadIdx.x;
  int e = i * 4;
  int c = e & 511, j = (e >> 9) & 63, ii = (e >> 15) & 63, b = e >> 21;
  us4v xv = *(const us4v*)&xb[(size_t)e];
  us4v mv = *(const us4v*)&mskip_bf[(size_t)e];
  f32x4 fv = *(const f32x4*)&fin[(size_t)((b * 64 + (ii >> 3) * 8 + (j >> 3)) << 9) + c];
  f32x4 r;
#pragma unroll
  for (int q = 0; q < 4; ++q) r[q] = bf2f(xv[q]) + fv[q] + bf2f(mv[q]);
  *(f32x4*)&out[(size_t)e] = r;
}

extern "C" void kernel_launch(void* const* d_in, const int* in_sizes, int n_in,
                              void* d_out, int out_size, void* d_ws, size_t ws_size,
                              hipStream_t stream) {
  const float* x     = (const float*)d_in[0];
  const float* lq    = (const float*)d_in[1];
  const float* lkv   = (const float*)d_in[2];
  const float* pe1   = (const float*)d_in[3];
  const float* pe2   = (const float*)d_in[4];
  const float* w_q   = (const float*)d_in[5];
  const float* b_q   = (const float*)d_in[6];
  const float* w_kvx = (const float*)d_in[7];
  const float* b_kvx = (const float*)d_in[8];
  const float* w_kvy = (const float*)d_in[9];
  const float* b_kvy = (const float*)d_in[10];
  const float* w_q2  = (const float*)d_in[11];
  const float* b_q2  = (const float*)d_in[12];
  const float* f1w1  = (const float*)d_in[13];
  const float* f1b1  = (const float*)d_in[14];
  const float* f1w2  = (const float*)d_in[15];
  const float* f1b2  = (const float*)d_in[16];
  const float* f2w1  = (const float*)d_in[17];
  const float* f2b1  = (const float*)d_in[18];
  const float* f2w2  = (const float*)d_in[19];
  const float* f2b2  = (const float*)d_in[20];
  float* out = (float*)d_out;

  char* ws = (char*)d_ws;
  size_t off = 0;
  auto alloc = [&](size_t bytes) {
    char* p = ws + off;
    off += (bytes + 255) & ~(size_t)255;
    return p;
  };
  ub16* xb    = (ub16*)alloc((size_t)32768 * 512 * 2);      // bf16 x; stays live to k_final
  ub16* mskip = (ub16*)alloc((size_t)32768 * 512 * 2);      // mlp1b output
  ub16* o1    = (ub16*)alloc((size_t)32768 * 512 * 2);      // reused as Kbuf after mlp1a
  ub16* VTb   = (ub16*)alloc((size_t)64 * 64 * 4096 * 2);   // h1 lives here until g4
  ub16* WqkT  = (ub16*)alloc((size_t)512 * 512 * 2);
  ub16* w1T   = (ub16*)alloc((size_t)512 * 512 * 2);
  ub16* w2T   = (ub16*)alloc((size_t)512 * 512 * 2);
  ub16* g1T   = (ub16*)alloc((size_t)512 * 512 * 2);
  ub16* g2T   = (ub16*)alloc((size_t)512 * 512 * 2);
  ub16* kvxT  = (ub16*)alloc((size_t)1024 * 512 * 2);
  ub16* k1    = (ub16*)alloc((size_t)8 * 64 * 64 * 2);
  ub16* v1T   = (ub16*)alloc((size_t)8 * 64 * 64 * 2);
  ub16* q2p   = (ub16*)alloc((size_t)8 * 64 * 64 * 2);
  float* bias1 = (float*)alloc(512 * 4);
  float* biass = (float*)alloc(512 * 4);
  float* m_part = (float*)alloc((size_t)1024 * 64 * 4);
  float* l_part = (float*)alloc((size_t)1024 * 64 * 4);
  float* cs_part = (float*)alloc((size_t)1024 * 64 * 4);
  float* o_part = (float*)alloc((size_t)1024 * 4096 * 4);
  ub16* fin0 = (ub16*)alloc((size_t)512 * 512 * 2);
  float* fin = (float*)alloc((size_t)512 * 512 * 4);
  ub16* h2 = (ub16*)alloc((size_t)512 * 512 * 2);
  ub16* Kbuf = o1;        // alias: o1 dead after mlp1a
  ub16* h1buf = VTb;      // alias: h1 dead before g4 writes VTb
  (void)in_sizes; (void)n_in; (void)out_size; (void)ws_size;

  const int n4 = (8 * 64 * 64 * 512) / 4;

  k_cvt<<<n4 / 256, 256, 0, stream>>>(x, xb);
  k_prep_wt<<<dim3(16, 8, 5), 256, 0, stream>>>(f1w1, f1w2, f2w1, f2w2, w_kvx,
                                                w1T, w2T, g1T, g2T, kvxT);
  k_prep_small<<<1536, 64, 0, stream>>>(lkv, w_kvy, b_kvy, lq, w_q, b_q, pe1,
                                        k1, v1T, bias1, q2p);
  k_prep_wqk<<<512, 256, 0, stream>>>(w_q2, b_q2, k1, WqkT, biass);
  k_s1a<<<1024, 256, 0, stream>>>(xb, WqkT, biass, v1T, bias1, o1);
  k_mlp1a<<<1024, 256, 0, stream>>>(o1, w1T, f1b1, h1buf);
  k_mlp1b<<<1024, 256, 0, stream>>>(h1buf, w2T, f1b2, xb, mskip);
  k_g4<<<2048, 256, 0, stream>>>(mskip, kvxT, b_kvx, Kbuf, VTb);
  k_attn2<<<dim3(4, 8, 8), 256, 0, stream>>>(q2p, Kbuf, VTb, m_part, l_part, cs_part, o_part);
  k_combine<<<256, 256, 0, stream>>>(m_part, l_part, cs_part, o_part, pe2, fin0);
  k_mlp1a<<<16, 256, 0, stream>>>(fin0, g1T, f2b1, h2);   // MLP2 layer 1
  k_mlp2b<<<16, 256, 0, stream>>>(h2, g2T, f2b2, fin);    // MLP2 layer 2
  k_final<<<n4 / 256, 256, 0, stream>>>(xb, fin, mskip, out);
}

// Round 14
// 319.140 us; speedup vs baseline: 1.0122x; 1.0122x over previous
//
#include <hip/hip_runtime.h>
#include <stdint.h>

typedef unsigned short ub16;
typedef __attribute__((ext_vector_type(8))) short short8;
typedef __attribute__((ext_vector_type(4))) float f32x4;
typedef __attribute__((ext_vector_type(4))) unsigned short us4v;

__device__ __forceinline__ float bf2f(ub16 u) {
  union { unsigned int i; float f; } v; v.i = ((unsigned int)u) << 16; return v.f;
}
__device__ __forceinline__ ub16 f2bf(float f) {
  union { float f; unsigned int i; } v; v.f = f;
  return (ub16)((v.i + 0x7FFFu + ((v.i >> 16) & 1u)) >> 16);
}
__device__ __forceinline__ f32x4 zero4() { f32x4 v = {0.f, 0.f, 0.f, 0.f}; return v; }
__device__ __forceinline__ f32x4 mfma16(short8 a, short8 b, f32x4 c) {
  return __builtin_amdgcn_mfma_f32_16x16x32_bf16(a, b, c, 0, 0, 0);
}
__device__ __forceinline__ float rmax16(float x) {
  x = fmaxf(x, __shfl_xor(x, 1)); x = fmaxf(x, __shfl_xor(x, 2));
  x = fmaxf(x, __shfl_xor(x, 4)); x = fmaxf(x, __shfl_xor(x, 8)); return x;
}
__device__ __forceinline__ float rsum16(float x) {
  x += __shfl_xor(x, 1); x += __shfl_xor(x, 2);
  x += __shfl_xor(x, 4); x += __shfl_xor(x, 8); return x;
}

// async global->LDS 16B (wave-uniform LDS base + lane*16 implicit)
__device__ __forceinline__ void gload16(const ub16* g, ub16* l) {
  __builtin_amdgcn_global_load_lds(
      (const __attribute__((address_space(1))) void*)g,
      (__attribute__((address_space(3))) void*)l, 16, 0, 0);
}

// Stage 128x64 bf16 tile via global_load_lds. LDS dest linear; GLOBAL source
// slot inverse-swizzled (slot ^= row&7) so swizzled ds_reads see right data.
__device__ __forceinline__ void stage_tile(const ub16* __restrict__ src, ub16* ldsbase,
                                           int wid, int lane) {
  const int rr = lane >> 3;
  const int slog = (lane & 7) ^ rr;
#pragma unroll
  for (int c = 0; c < 4; ++c) {
    int chunk = wid * 4 + c;
    int row = chunk * 8 + rr;
    gload16(src + (size_t)row * 512 + slog * 8,
            (ub16*)((char*)ldsbase + chunk * 1024));
  }
}

// 128x128 4-wave compute. SWAP=true: acc = mfma(B,A) -> D rows index N,
// cols index M (both fragments share the same lane->(row,k) load layout).
template<bool SWAP>
__device__ __forceinline__ void gemm_compute(const ub16* Ab, const ub16* Bb, int wm, int wn,
                                             int l15, int lg, f32x4 acc[4][4]) {
#pragma unroll
  for (int kf = 0; kf < 2; ++kf) {
    short8 af[4], bfr[4];
#pragma unroll
    for (int mf = 0; mf < 4; ++mf) {
      int row = wm * 64 + mf * 16 + l15;
      af[mf] = *(const short8*)((const char*)Ab + row * 128 +
                                ((kf * 64 + lg * 16) ^ ((row & 7) << 4)));
    }
#pragma unroll
    for (int nf = 0; nf < 4; ++nf) {
      int row = wn * 64 + nf * 16 + l15;
      bfr[nf] = *(const short8*)((const char*)Bb + row * 128 +
                                 ((kf * 64 + lg * 16) ^ ((row & 7) << 4)));
    }
#pragma unroll
    for (int mf = 0; mf < 4; ++mf)
#pragma unroll
      for (int nf = 0; nf < 4; ++nf)
        acc[mf][nf] = SWAP ? mfma16(bfr[nf], af[mf], acc[mf][nf])
                           : mfma16(af[mf], bfr[nf], acc[mf][nf]);
  }
}

// m97-structure K=512 loop: single 32KB buffer, stage -> vmcnt(0)+barrier ->
// compute -> barrier. Cross-block overlap (5 blocks/CU) hides the drain.
template<bool SWAP>
__device__ __forceinline__ void gemm_k512(const ub16* Ap, const ub16* Bp, ub16* lds,
                                          int wid, int lane, int wm, int wn, int l15, int lg,
                                          f32x4 acc[4][4]) {
  ub16* A0 = lds;
  ub16* B0 = lds + 8192;
#pragma unroll
  for (int kb = 0; kb < 8; ++kb) {
    stage_tile(Ap + kb * 64, A0, wid, lane);
    stage_tile(Bp + kb * 64, B0, wid, lane);
    asm volatile("s_waitcnt vmcnt(0)" ::: "memory");
    __syncthreads();
    gemm_compute<SWAP>(A0, B0, wm, wn, l15, lg, acc);
    __syncthreads();
  }
}

// XCD-bijective remap (nwg%8==0), n-tile fastest within an XCD.
__device__ __forceinline__ void xcd_remap(int nx, int& m0, int& n0) {
  int bid = blockIdx.x, nwg = gridDim.x;
  int cpx = nwg >> 3;
  int wgid = (bid & 7) * cpx + (bid >> 3);
  n0 = (wgid % nx) * 128;
  m0 = (wgid / nx) * 128;
}

// ---------------- P0: x (fp32) -> xb (bf16) ----------------
__global__ void k_cvt(const float* __restrict__ x, ub16* __restrict__ xb) {
  int i = blockIdx.x * 256 + threadIdx.x;
  f32x4 v = *(const f32x4*)&x[(size_t)i * 4];
  us4v o;
#pragma unroll
  for (int e = 0; e < 4; ++e) o[e] = f2bf(v[e]);
  *(us4v*)&xb[(size_t)i * 4] = o;
}

// ---------------- P1: weight transpose + bf16  WT[n][k] = w[k][n] ----------------
__global__ void k_prep_wt(const float* s0, const float* s1, const float* s2,
                          const float* s3, const float* s4,
                          ub16* d0, ub16* d1, ub16* d2, ub16* d3, ub16* d4) {
  const float* src; ub16* dst; int N;
  switch (blockIdx.z) {
    case 0: src = s0; dst = d0; N = 512; break;
    case 1: src = s1; dst = d1; N = 512; break;
    case 2: src = s2; dst = d2; N = 512; break;
    case 3: src = s3; dst = d3; N = 512; break;
    default: src = s4; dst = d4; N = 1024; break;
  }
  int n0 = blockIdx.x * 64, k0 = blockIdx.y * 64;
  if (n0 >= N) return;
  __shared__ float tile[64][65];
#pragma unroll
  for (int i = 0; i < 16; ++i) {
    int idx = i * 256 + threadIdx.x, r = idx >> 6, c = idx & 63;
    tile[r][c] = src[(size_t)(k0 + r) * N + n0 + c];
  }
  __syncthreads();
#pragma unroll
  for (int i = 0; i < 16; ++i) {
    int idx = i * 256 + threadIdx.x, r = idx >> 6, c = idx & 63;
    dst[(size_t)(n0 + r) * 512 + k0 + c] = f2bf(tile[c][r]);
  }
}

// ---------------- P2: kv1 = lkv@w_kvy+b ; q2p = lq@w_q+b ; k1 (scaled), v1T, bias1 ----------------
__global__ void k_prep_small(const float* __restrict__ lkv, const float* __restrict__ w_kvy,
                             const float* __restrict__ b_kvy, const float* __restrict__ lq,
                             const float* __restrict__ w_q, const float* __restrict__ b_q,
                             const float* __restrict__ pe1,
                             ub16* __restrict__ k1, ub16* __restrict__ v1T,
                             float* __restrict__ bias1, ub16* __restrict__ q2p) {
  int j = blockIdx.x, t = threadIdx.x;  // 64 threads
  __shared__ float wcol[512];
  __shared__ float red[64];
  const float* W; const float* src; float bias; int NC, jj;
  if (j < 1024) { W = w_kvy; NC = 1024; src = lkv; jj = j;        bias = b_kvy[j]; }
  else          { W = w_q;   NC = 512;  src = lq;  jj = j - 1024; bias = b_q[jj]; }
#pragma unroll
  for (int e = 0; e < 8; ++e) wcol[t * 8 + e] = W[(size_t)(t * 8 + e) * NC + jj];
  __syncthreads();
  float acc = bias;
  for (int k = 0; k < 512; ++k) acc += src[(size_t)t * 512 + k] * wcol[k];
  if (j < 512) {
    int h = j >> 6, d = j & 63;
    k1[(size_t)(h * 64 + t) * 64 + d] = f2bf(acc * 0.125f);
  } else if (j < 1024) {
    int h = (j - 512) >> 6, d = (j - 512) & 63;
    v1T[(size_t)(h * 64 + d) * 64 + t] = f2bf(acc);
    red[t] = pe1[h * 64 + t] * acc;
    __syncthreads();
    for (int s = 32; s > 0; s >>= 1) { if (t < s) red[t] += red[t + s]; __syncthreads(); }
    if (t == 0) bias1[h * 64 + d] = red[0];
  } else {
    int h = jj >> 6, d = jj & 63;
    q2p[(size_t)(h * 64 + t) * 64 + d] = f2bf(acc * 0.125f);
  }
}

// ---------------- P3: WqkT + bias_s ----------------
__global__ __launch_bounds__(256) void k_prep_wqk(
    const float* __restrict__ w_q2, const float* __restrict__ b_q2,
    const ub16* __restrict__ k1, ub16* __restrict__ WqkT,
    float* __restrict__ biass) {
  int ha = blockIdx.x, h = ha >> 6, t = threadIdx.x;
  __shared__ float kr[64];
  if (t < 64) kr[t] = bf2f(k1[(size_t)ha * 64 + t]);
  __syncthreads();
#pragma unroll
  for (int i = 0; i < 2; ++i) {
    int kin = t + i * 256;
    const float* wrow = &w_q2[(size_t)kin * 512 + h * 64];
    float acc = 0.f;
#pragma unroll
    for (int d4 = 0; d4 < 16; ++d4) {
      f32x4 wv = *(const f32x4*)&wrow[d4 * 4];
      acc += wv[0] * kr[d4 * 4] + wv[1] * kr[d4 * 4 + 1] +
             wv[2] * kr[d4 * 4 + 2] + wv[3] * kr[d4 * 4 + 3];
    }
    WqkT[(size_t)ha * 512 + kin] = f2bf(acc);
  }
  if (t == 0) {
    float acc = 0.f;
    for (int d = 0; d < 64; ++d) acc += b_q2[h * 64 + d] * kr[d];
    biass[ha] = acc;
  }
}

// ---------------- S1a: scores GEMM (xb@Wqk+bias_s) + per-wave softmax + PV + bias1 -> o1 ----------------
__global__ __launch_bounds__(256) void k_s1a(
    const ub16* __restrict__ xb, const ub16* __restrict__ WqkT,
    const float* __restrict__ biass, const ub16* __restrict__ v1T,
    const float* __restrict__ bias1, ub16* __restrict__ o1) {
  __shared__ ub16 lds[16384];  // 32KB staging; reused as 4x8KB P buffers
  const int tid = threadIdx.x, lane = tid & 63, wid = tid >> 6;
  const int wm = wid >> 1, wn = wid & 1;
  const int l15 = lane & 15, lg = lane >> 4;
  int m0, n0;
  xcd_remap(4, m0, n0);

  f32x4 acc[4][4];
#pragma unroll
  for (int a = 0; a < 4; ++a)
#pragma unroll
    for (int b = 0; b < 4; ++b) acc[a][b] = zero4();

  gemm_k512<false>(xb + (size_t)m0 * 512, WqkT + (size_t)n0 * 512, lds,
                   wid, lane, wm, wn, l15, lg, acc);

  __syncthreads();
  const int h = (n0 >> 6) + wn;
  char* Pl = (char*)lds + wid * 8192;
  float bsv[4];
#pragma unroll
  for (int nf = 0; nf < 4; ++nf) bsv[nf] = biass[h * 64 + nf * 16 + l15];
  float dinv[4][4];
#pragma unroll
  for (int mf = 0; mf < 4; ++mf) {
#pragma unroll
    for (int r = 0; r < 4; ++r) {
      float s0 = acc[mf][0][r] + bsv[0], s1 = acc[mf][1][r] + bsv[1];
      float s2 = acc[mf][2][r] + bsv[2], s3 = acc[mf][3][r] + bsv[3];
      float mx = rmax16(fmaxf(fmaxf(s0, s1), fmaxf(s2, s3)));
      float p0 = __expf(s0 - mx), p1 = __expf(s1 - mx);
      float p2 = __expf(s2 - mx), p3 = __expf(s3 - mx);
      float sm = rsum16(p0 + p1 + p2 + p3);
      dinv[mf][r] = 1.0f / sm;
      int tr = mf * 16 + lg * 4 + r;
      char* rb = Pl + tr * 128;
      int sw = (tr & 7) << 4;
      *(ub16*)(rb + (((0 * 16 + l15) * 2) ^ sw)) = f2bf(p0);
      *(ub16*)(rb + (((1 * 16 + l15) * 2) ^ sw)) = f2bf(p1);
      *(ub16*)(rb + (((2 * 16 + l15) * 2) ^ sw)) = f2bf(p2);
      *(ub16*)(rb + (((3 * 16 + l15) * 2) ^ sw)) = f2bf(p3);
    }
  }
  short8 pa[4][2], vb[4][2];
#pragma unroll
  for (int mf = 0; mf < 4; ++mf) {
    int row = mf * 16 + l15;
#pragma unroll
    for (int kf = 0; kf < 2; ++kf)
      pa[mf][kf] = *(const short8*)(Pl + row * 128 + ((kf * 64 + lg * 16) ^ ((row & 7) << 4)));
  }
#pragma unroll
  for (int nf = 0; nf < 4; ++nf)
#pragma unroll
    for (int kf = 0; kf < 2; ++kf)
      vb[nf][kf] = *(const short8*)&v1T[(size_t)(h * 64 + nf * 16 + l15) * 64 + kf * 32 + lg * 8];
  f32x4 oacc[4][4];
#pragma unroll
  for (int a = 0; a < 4; ++a)
#pragma unroll
    for (int b = 0; b < 4; ++b) oacc[a][b] = zero4();
#pragma unroll
  for (int kf = 0; kf < 2; ++kf)
#pragma unroll
    for (int mf = 0; mf < 4; ++mf)
#pragma unroll
      for (int nf = 0; nf < 4; ++nf)
        oacc[mf][nf] = mfma16(pa[mf][kf], vb[nf][kf], oacc[mf][nf]);
  float b1v[4];
#pragma unroll
  for (int nf = 0; nf < 4; ++nf) b1v[nf] = bias1[h * 64 + nf * 16 + l15];
#pragma unroll
  for (int mf = 0; mf < 4; ++mf)
#pragma unroll
    for (int nf = 0; nf < 4; ++nf)
#pragma unroll
      for (int r = 0; r < 4; ++r) {
        float val = oacc[mf][nf][r] * dinv[mf][r] + b1v[nf];
        o1[(size_t)(m0 + wm * 64 + mf * 16 + lg * 4 + r) * 512 + h * 64 + nf * 16 + l15] = f2bf(val);
      }
}

// ---------------- MLP1a (also MLP2 layer 1): swap epilogue, out = silu(in@W1+b1) ----------------
__global__ __launch_bounds__(256) void k_mlp1a(
    const ub16* __restrict__ in, const ub16* __restrict__ W1T,
    const float* __restrict__ b1, ub16* __restrict__ h1) {
  __shared__ ub16 lds[16384];
  const int tid = threadIdx.x, lane = tid & 63, wid = tid >> 6;
  const int wm = wid >> 1, wn = wid & 1;
  const int l15 = lane & 15, lg = lane >> 4;
  int m0, n0;
  xcd_remap(4, m0, n0);
  f32x4 acc[4][4];
#pragma unroll
  for (int a = 0; a < 4; ++a)
#pragma unroll
    for (int b = 0; b < 4; ++b) acc[a][b] = zero4();
  gemm_k512<true>(in + (size_t)m0 * 512, W1T + (size_t)n0 * 512, lds,
                  wid, lane, wm, wn, l15, lg, acc);
#pragma unroll
  for (int mf = 0; mf < 4; ++mf) {
    int m = m0 + wm * 64 + mf * 16 + l15;
#pragma unroll
    for (int nf = 0; nf < 4; ++nf) {
      int nb = n0 + wn * 64 + nf * 16 + lg * 4;
      f32x4 bb = *(const f32x4*)&b1[nb];
      us4v pk;
#pragma unroll
      for (int r = 0; r < 4; ++r) {
        float v = acc[mf][nf][r] + bb[r];
        v = v / (1.0f + __expf(-v));  // silu
        pk[r] = f2bf(v);
      }
      *(us4v*)&h1[(size_t)m * 512 + nb] = pk;
    }
  }
}

// ---------------- MLP1b: mskip = h1@W2 + b2 + xb(bf16) -> separate bf16 mskip ----------------
__global__ __launch_bounds__(256) void k_mlp1b(
    const ub16* __restrict__ h1, const ub16* __restrict__ W2T,
    const float* __restrict__ b2, const ub16* __restrict__ xb,
    ub16* __restrict__ mskip) {
  __shared__ ub16 lds[16384];
  const int tid = threadIdx.x, lane = tid & 63, wid = tid >> 6;
  const int wm = wid >> 1, wn = wid & 1;
  const int l15 = lane & 15, lg = lane >> 4;
  int m0, n0;
  xcd_remap(4, m0, n0);
  f32x4 acc[4][4];
#pragma unroll
  for (int a = 0; a < 4; ++a)
#pragma unroll
    for (int b = 0; b < 4; ++b) acc[a][b] = zero4();
  gemm_k512<true>(h1 + (size_t)m0 * 512, W2T + (size_t)n0 * 512, lds,
                  wid, lane, wm, wn, l15, lg, acc);
#pragma unroll
  for (int mf = 0; mf < 4; ++mf) {
    int m = m0 + wm * 64 + mf * 16 + l15;
#pragma unroll
    for (int nf = 0; nf < 4; ++nf) {
      int nb = n0 + wn * 64 + nf * 16 + lg * 4;
      f32x4 bb = *(const f32x4*)&b2[nb];
      size_t idx = (size_t)m * 512 + nb;
      us4v xv = *(const us4v*)&xb[idx];
      us4v pk;
#pragma unroll
      for (int r = 0; r < 4; ++r)
        pk[r] = f2bf(acc[mf][nf][r] + bb[r] + bf2f(xv[r]));
      *(us4v*)&mskip[idx] = pk;
    }
  }
}

// ---------------- MLP2b: fin = h2@W2 + b2 (fp32) ----------------
__global__ __launch_bounds__(256) void k_mlp2b(
    const ub16* __restrict__ h2, const ub16* __restrict__ W2T,
    const float* __restrict__ b2, float* __restrict__ fin) {
  __shared__ ub16 lds[16384];
  const int tid = threadIdx.x, lane = tid & 63, wid = tid >> 6;
  const int wm = wid >> 1, wn = wid & 1;
  const int l15 = lane & 15, lg = lane >> 4;
  int m0, n0;
  xcd_remap(4, m0, n0);
  f32x4 acc[4][4];
#pragma unroll
  for (int a = 0; a < 4; ++a)
#pragma unroll
    for (int b = 0; b < 4; ++b) acc[a][b] = zero4();
  gemm_k512<true>(h2 + (size_t)m0 * 512, W2T + (size_t)n0 * 512, lds,
                  wid, lane, wm, wn, l15, lg, acc);
#pragma unroll
  for (int mf = 0; mf < 4; ++mf) {
    int m = m0 + wm * 64 + mf * 16 + l15;
#pragma unroll
    for (int nf = 0; nf < 4; ++nf) {
      int nb = n0 + wn * 64 + nf * 16 + lg * 4;
      f32x4 bb = *(const f32x4*)&b2[nb];
      f32x4 ov;
#pragma unroll
      for (int r = 0; r < 4; ++r) ov[r] = acc[mf][nf][r] + bb[r];
      *(f32x4*)&fin[(size_t)m * 512 + nb] = ov;
    }
  }
}

// ---------------- G4: kv = mskip@w_kvx + b -> Kb (swap, packed d) and VTb (normal, packed t) ----------------
__global__ __launch_bounds__(256) void k_g4(
    const ub16* __restrict__ mskip_bf, const ub16* __restrict__ WT,
    const float* __restrict__ bias, ub16* __restrict__ Kb, ub16* __restrict__ VTb) {
  __shared__ ub16 lds[16384];
  const int tid = threadIdx.x, lane = tid & 63, wid = tid >> 6;
  const int wm = wid >> 1, wn = wid & 1;
  const int l15 = lane & 15, lg = lane >> 4;
  int m0, n0;
  xcd_remap(8, m0, n0);
  f32x4 acc[4][4];
#pragma unroll
  for (int a = 0; a < 4; ++a)
#pragma unroll
    for (int b = 0; b < 4; ++b) acc[a][b] = zero4();
  const int ncb = n0 + wn * 64;
  if (n0 < 512) {  // K half: swapped -> 4 consecutive d per 8B store
    gemm_k512<true>(mskip_bf + (size_t)m0 * 512, WT + (size_t)n0 * 512, lds,
                    wid, lane, wm, wn, l15, lg, acc);
    const int hh = ncb >> 6;
#pragma unroll
    for (int mf = 0; mf < 4; ++mf) {
      int m = m0 + wm * 64 + mf * 16 + l15;
      int b = m >> 12, t = m & 4095;
#pragma unroll
      for (int nf = 0; nf < 4; ++nf) {
        int d0 = nf * 16 + lg * 4;
        f32x4 bb = *(const f32x4*)&bias[ncb + d0];
        us4v pk;
#pragma unroll
        for (int r = 0; r < 4; ++r) pk[r] = f2bf(acc[mf][nf][r] + bb[r]);
        *(us4v*)&Kb[((size_t)(b * 8 + hh) * 4096 + t) * 64 + d0] = pk;
      }
    }
  } else {  // V half: normal -> 4 consecutive t per 8B store
    gemm_k512<false>(mskip_bf + (size_t)m0 * 512, WT + (size_t)n0 * 512, lds,
                     wid, lane, wm, wn, l15, lg, acc);
    const int hv = (ncb >> 6) - 8;
#pragma unroll
    for (int mf = 0; mf < 4; ++mf) {
      int m4 = m0 + wm * 64 + mf * 16 + lg * 4;
      int b = m4 >> 12, t = m4 & 4095;
#pragma unroll
      for (int nf = 0; nf < 4; ++nf) {
        int d = nf * 16 + l15;
        float bb = bias[ncb + d];
        us4v pk;
#pragma unroll
        for (int r = 0; r < 4; ++r) pk[r] = f2bf(acc[mf][nf][r] + bb);
        *(us4v*)&VTb[((size_t)(b * 8 + hv) * 64 + d) * 4096 + t] = pk;
      }
    }
  }
}

// ---------------- A2: flash split attention (16 splits x 256 tokens per (b,h)), bf16 o_part ----------------
__global__ __launch_bounds__(256) void k_attn2(
    const ub16* __restrict__ q2p, const ub16* __restrict__ Kb, const ub16* __restrict__ VTb,
    float* __restrict__ m_part, float* __restrict__ l_part,
    float* __restrict__ cs_part, ub16* __restrict__ o_part) {
  const int tid = threadIdx.x, lane = tid & 63, wid = tid >> 6;
  const int l15 = lane & 15, lg = lane >> 4;
  const int b = blockIdx.z, h = blockIdx.y;
  const int split = blockIdx.x * 4 + wid;  // 0..15
  __shared__ ub16 plds[4 * 64 * 40];
  ub16* pl = plds + wid * 64 * 40;
  short8 qa[4][2];
#pragma unroll
  for (int mf = 0; mf < 4; ++mf)
#pragma unroll
    for (int kf = 0; kf < 2; ++kf)
      qa[mf][kf] = *(const short8*)&q2p[(size_t)(h * 64 + mf * 16 + l15) * 64 + kf * 32 + lg * 8];
  float mr[4][4], lr[4][4], cs[4] = {0.f, 0.f, 0.f, 0.f};
  f32x4 oa[4][4];
#pragma unroll
  for (int a = 0; a < 4; ++a)
#pragma unroll
    for (int r = 0; r < 4; ++r) { mr[a][r] = -1e30f; lr[a][r] = 0.f; }
#pragma unroll
  for (int a = 0; a < 4; ++a)
#pragma unroll
    for (int n = 0; n < 4; ++n) oa[a][n] = zero4();
  const size_t kbase = (size_t)(b * 8 + h) * 4096 * 64;
  const size_t vbase = (size_t)(b * 8 + h) * 64 * 4096;
  for (int c = 0; c < 8; ++c) {
    int tb = split * 256 + c * 32;
    short8 kbf[2][2];
#pragma unroll
    for (int nf = 0; nf < 2; ++nf)
#pragma unroll
      for (int kf = 0; kf < 2; ++kf)
        kbf[nf][kf] = *(const short8*)&Kb[kbase + (size_t)(tb + nf * 16 + l15) * 64 + kf * 32 + lg * 8];
    f32x4 sc[4][2];
#pragma unroll
    for (int a = 0; a < 4; ++a)
#pragma unroll
      for (int n = 0; n < 2; ++n) sc[a][n] = zero4();
#pragma unroll
    for (int kf = 0; kf < 2; ++kf)
#pragma unroll
      for (int mf = 0; mf < 4; ++mf)
#pragma unroll
        for (int nf = 0; nf < 2; ++nf)
          sc[mf][nf] = mfma16(qa[mf][kf], kbf[nf][kf], sc[mf][nf]);
    float al[4][4];
#pragma unroll
    for (int mf = 0; mf < 4; ++mf)
#pragma unroll
      for (int r = 0; r < 4; ++r) {
        float cm = rmax16(fmaxf(sc[mf][0][r], sc[mf][1][r]));
        float nm = fmaxf(mr[mf][r], cm);
        float a_ = __expf(mr[mf][r] - nm);
        float p0 = __expf(sc[mf][0][r] - nm), p1 = __expf(sc[mf][1][r] - nm);
        float rs = rsum16(p0 + p1);
        lr[mf][r] = lr[mf][r] * a_ + rs;
        mr[mf][r] = nm;
        al[mf][r] = a_;
        int ar = mf * 16 + lg * 4 + r;
        char* rb = (char*)pl + ar * 80;
        *(ub16*)(rb + (0 * 16 + l15) * 2) = f2bf(p0);
        *(ub16*)(rb + (1 * 16 + l15) * 2) = f2bf(p1);
      }
#pragma unroll
    for (int mf = 0; mf < 4; ++mf)
#pragma unroll
      for (int nf = 0; nf < 4; ++nf)
#pragma unroll
        for (int r = 0; r < 4; ++r) oa[mf][nf][r] *= al[mf][r];
    short8 pa[4], vb[4];
#pragma unroll
    for (int mf = 0; mf < 4; ++mf)
      pa[mf] = *(const short8*)((char*)pl + (mf * 16 + l15) * 80 + lg * 16);
#pragma unroll
    for (int nf = 0; nf < 4; ++nf) {
      vb[nf] = *(const short8*)&VTb[vbase + (size_t)(nf * 16 + l15) * 4096 + tb + lg * 8];
#pragma unroll
      for (int e = 0; e < 8; ++e) cs[nf] += bf2f((ub16)vb[nf][e]);
    }
#pragma unroll
    for (int mf = 0; mf < 4; ++mf)
#pragma unroll
      for (int nf = 0; nf < 4; ++nf)
        oa[mf][nf] = mfma16(pa[mf], vb[nf], oa[mf][nf]);
  }
#pragma unroll
  for (int nf = 0; nf < 4; ++nf) {
    cs[nf] += __shfl_xor(cs[nf], 16);
    cs[nf] += __shfl_xor(cs[nf], 32);
  }
  const int pidx = (b * 8 + h) * 16 + split;
  if (lg == 0) {
#pragma unroll
    for (int nf = 0; nf < 4; ++nf) cs_part[(size_t)pidx * 64 + nf * 16 + l15] = cs[nf];
  }
  if (l15 == 0) {
#pragma unroll
    for (int mf = 0; mf < 4; ++mf)
#pragma unroll
      for (int r = 0; r < 4; ++r) {
        int a = mf * 16 + lg * 4 + r;
        m_part[(size_t)pidx * 64 + a] = mr[mf][r];
        l_part[(size_t)pidx * 64 + a] = lr[mf][r];
      }
  }
#pragma unroll
  for (int mf = 0; mf < 4; ++mf)
#pragma unroll
    for (int nf = 0; nf < 4; ++nf)
#pragma unroll
      for (int r = 0; r < 4; ++r) {
        int a = mf * 16 + lg * 4 + r, d = nf * 16 + l15;
        o_part[(size_t)pidx * 4096 + a * 64 + d] = f2bf(oa[mf][nf][r]);
      }
}

// ---------------- C2: combine 16 splits (bf16 o_part) + pe2*colsumV -> fin0; 4 blocks per (b,h) ----------------
__global__ __launch_bounds__(256) void k_combine(
    const float* __restrict__ m_part, const float* __restrict__ l_part,
    const float* __restrict__ cs_part, const ub16* __restrict__ o_part,
    const float* __restrict__ pe2, ub16* __restrict__ fin0) {
  int bh = blockIdx.x >> 2, q = blockIdx.x & 3;
  int b = bh >> 3, h = bh & 7;
  int t = threadIdx.x;
  __shared__ float wsp[16][64];
  __shared__ float linv[64];
  __shared__ float cst[64];
  int base = bh * 16;
  if (t < 64) {
    int a = t;
    float M = -1e30f;
    for (int s = 0; s < 16; ++s) M = fmaxf(M, m_part[(size_t)(base + s) * 64 + a]);
    float L = 0.f;
    for (int s = 0; s < 16; ++s) {
      float w = __expf(m_part[(size_t)(base + s) * 64 + a] - M);
      wsp[s][a] = w;
      L += l_part[(size_t)(base + s) * 64 + a] * w;
    }
    linv[a] = 1.0f / L;
  } else if (t < 128) {
    int d = t - 64;
    float c = 0.f;
    for (int s = 0; s < 16; ++s) c += cs_part[(size_t)(base + s) * 64 + d];
    cst[d] = c;
  }
  __syncthreads();
#pragma unroll
  for (int i = 0; i < 4; ++i) {
    int e = q * 1024 + i * 256 + t, a = e >> 6, d = e & 63;
    float acc = 0.f;
#pragma unroll
    for (int s = 0; s < 16; ++s)
      acc += bf2f(o_part[(size_t)(base + s) * 4096 + e]) * wsp[s][a];
    float val = acc * linv[a] + pe2[h * 64 + a] * cst[d];
    fin0[(size_t)(b * 64 + a) * 512 + h * 64 + d] = f2bf(val);
  }
}

// ---------------- F: out = xb(bf16) + fin_upsampled + mskip(bf16) ----------------
__global__ void k_final(const ub16* __restrict__ xb, const float* __restrict__ fin,
                        const ub16* __restrict__ mskip_bf, float* __restrict__ out) {
  int i = blockIdx.x * 256 + threadIdx.x;
  int e = i * 4;
  int c = e & 511, j = (e >> 9) & 63, ii = (e >> 15) & 63, b = e >> 21;
  us4v xv = *(const us4v*)&xb[(size_t)e];
  us4v mv = *(const us4v*)&mskip_bf[(size_t)e];
  f32x4 fv = *(const f32x4*)&fin[(size_t)((b * 64 + (ii >> 3) * 8 + (j >> 3)) << 9) + c];
  f32x4 r;
#pragma unroll
  for (int q = 0; q < 4; ++q) r[q] = bf2f(xv[q]) + fv[q] + bf2f(mv[q]);
  *(f32x4*)&out[(size_t)e] = r;
}

extern "C" void kernel_launch(void* const* d_in, const int* in_sizes, int n_in,
                              void* d_out, int out_size, void* d_ws, size_t ws_size,
                              hipStream_t stream) {
  const float* x     = (const float*)d_in[0];
  const float* lq    = (const float*)d_in[1];
  const float* lkv   = (const float*)d_in[2];
  const float* pe1   = (const float*)d_in[3];
  const float* pe2   = (const float*)d_in[4];
  const float* w_q   = (const float*)d_in[5];
  const float* b_q   = (const float*)d_in[6];
  const float* w_kvx = (const float*)d_in[7];
  const float* b_kvx = (const float*)d_in[8];
  const float* w_kvy = (const float*)d_in[9];
  const float* b_kvy = (const float*)d_in[10];
  const float* w_q2  = (const float*)d_in[11];
  const float* b_q2  = (const float*)d_in[12];
  const float* f1w1  = (const float*)d_in[13];
  const float* f1b1  = (const float*)d_in[14];
  const float* f1w2  = (const float*)d_in[15];
  const float* f1b2  = (const float*)d_in[16];
  const float* f2w1  = (const float*)d_in[17];
  const float* f2b1  = (const float*)d_in[18];
  const float* f2w2  = (const float*)d_in[19];
  const float* f2b2  = (const float*)d_in[20];
  float* out = (float*)d_out;

  char* ws = (char*)d_ws;
  size_t off = 0;
  auto alloc = [&](size_t bytes) {
    char* p = ws + off;
    off += (bytes + 255) & ~(size_t)255;
    return p;
  };
  ub16* xb    = (ub16*)alloc((size_t)32768 * 512 * 2);      // bf16 x; stays live to k_final
  ub16* mskip = (ub16*)alloc((size_t)32768 * 512 * 2);      // mlp1b output
  ub16* o1    = (ub16*)alloc((size_t)32768 * 512 * 2);      // reused as Kbuf after mlp1a
  ub16* VTb   = (ub16*)alloc((size_t)64 * 64 * 4096 * 2);   // h1 lives here until g4
  ub16* WqkT  = (ub16*)alloc((size_t)512 * 512 * 2);
  ub16* w1T   = (ub16*)alloc((size_t)512 * 512 * 2);
  ub16* w2T   = (ub16*)alloc((size_t)512 * 512 * 2);
  ub16* g1T   = (ub16*)alloc((size_t)512 * 512 * 2);
  ub16* g2T   = (ub16*)alloc((size_t)512 * 512 * 2);
  ub16* kvxT  = (ub16*)alloc((size_t)1024 * 512 * 2);
  ub16* k1    = (ub16*)alloc((size_t)8 * 64 * 64 * 2);
  ub16* v1T   = (ub16*)alloc((size_t)8 * 64 * 64 * 2);
  ub16* q2p   = (ub16*)alloc((size_t)8 * 64 * 64 * 2);
  float* bias1 = (float*)alloc(512 * 4);
  float* biass = (float*)alloc(512 * 4);
  float* m_part = (float*)alloc((size_t)1024 * 64 * 4);
  float* l_part = (float*)alloc((size_t)1024 * 64 * 4);
  float* cs_part = (float*)alloc((size_t)1024 * 64 * 4);
  ub16* o_part = (ub16*)alloc((size_t)1024 * 4096 * 2);
  ub16* fin0 = (ub16*)alloc((size_t)512 * 512 * 2);
  float* fin = (float*)alloc((size_t)512 * 512 * 4);
  ub16* h2 = (ub16*)alloc((size_t)512 * 512 * 2);
  ub16* Kbuf = o1;        // alias: o1 dead after mlp1a
  ub16* h1buf = VTb;      // alias: h1 dead before g4 writes VTb
  (void)in_sizes; (void)n_in; (void)out_size; (void)ws_size;

  const int n4 = (8 * 64 * 64 * 512) / 4;

  k_cvt<<<n4 / 256, 256, 0, stream>>>(x, xb);
  k_prep_wt<<<dim3(16, 8, 5), 256, 0, stream>>>(f1w1, f1w2, f2w1, f2w2, w_kvx,
                                                w1T, w2T, g1T, g2T, kvxT);
  k_prep_small<<<1536, 64, 0, stream>>>(lkv, w_kvy, b_kvy, lq, w_q, b_q, pe1,
                                        k1, v1T, bias1, q2p);
  k_prep_wqk<<<512, 256, 0, stream>>>(w_q2, b_q2, k1, WqkT, biass);
  k_s1a<<<1024, 256, 0, stream>>>(xb, WqkT, biass, v1T, bias1, o1);
  k_mlp1a<<<1024, 256, 0, stream>>>(o1, w1T, f1b1, h1buf);
  k_mlp1b<<<1024, 256, 0, stream>>>(h1buf, w2T, f1b2, xb, mskip);
  k_g4<<<2048, 256, 0, stream>>>(mskip, kvxT, b_kvx, Kbuf, VTb);
  k_attn2<<<dim3(4, 8, 8), 256, 0, stream>>>(q2p, Kbuf, VTb, m_part, l_part, cs_part, o_part);
  k_combine<<<256, 256, 0, stream>>>(m_part, l_part, cs_part, o_part, pe2, fin0);
  k_mlp1a<<<16, 256, 0, stream>>>(fin0, g1T, f2b1, h2);   // MLP2 layer 1
  k_mlp2b<<<16, 256, 0, stream>>>(h2, g2T, f2b2, fin);    // MLP2 layer 2
  k_final<<<n4 / 256, 256, 0, stream>>>(xb, fin, mskip, out);
}